// Round 1
// baseline (1116.164 us; speedup 1.0000x reference)
//
#include <hip/hip_runtime.h>
#include <cstddef>
#include <cstdint>

// Problem constants (B, L, D, H) = (2, 2048, 1024, 16), KD = 64.
#define L_SEQ   2048
#define D_MODEL 1024
#define NH      16
#define HKD     64
#define TD3     3072
#define NBATCH  2

// ---------------------------------------------------------------------------
// fp32 GEMM: C[M,N] = A[M,K] @ B[K,N], row-major. Tile 128x128, BK=16,
// 256 threads, 8x8 per-thread register tile. M,N % 128 == 0, K % 16 == 0.
// ---------------------------------------------------------------------------
__global__ __launch_bounds__(256)
void gemm_f32(const float* __restrict__ A, const float* __restrict__ Bm,
              float* __restrict__ C, int M, int N, int K) {
  // stride 132 floats = 528 B = 33*16 B -> float4-aligned rows, +4 pad kills
  // power-of-2 bank cycling.
  __shared__ float As[16][132];  // transposed A tile: As[k][m]
  __shared__ float Bs[16][132];  // Bs[k][n]

  const int t = threadIdx.x;
  const int tx = t & 15, ty = t >> 4;
  const int row0 = blockIdx.y * 128, col0 = blockIdx.x * 128;

  // A-load mapping: rows tr, tr+64; 4 cols starting at tk4
  const int tr = t >> 2, tk4 = (t & 3) * 4;
  // B-load mapping: rows tkr, tkr+8; 4 cols starting at tc4
  const int tc4 = (t & 31) * 4, tkr = t >> 5;

  float acc[8][8];
#pragma unroll
  for (int i = 0; i < 8; ++i)
#pragma unroll
    for (int j = 0; j < 8; ++j) acc[i][j] = 0.f;

  for (int k0 = 0; k0 < K; k0 += 16) {
    const float4 a0 = *(const float4*)(A + (size_t)(row0 + tr) * K + k0 + tk4);
    const float4 a1 = *(const float4*)(A + (size_t)(row0 + tr + 64) * K + k0 + tk4);
    const float4 b0 = *(const float4*)(Bm + (size_t)(k0 + tkr) * N + col0 + tc4);
    const float4 b1 = *(const float4*)(Bm + (size_t)(k0 + tkr + 8) * N + col0 + tc4);
    __syncthreads();  // previous iteration's compute reads are done
    As[tk4 + 0][tr] = a0.x; As[tk4 + 1][tr] = a0.y;
    As[tk4 + 2][tr] = a0.z; As[tk4 + 3][tr] = a0.w;
    As[tk4 + 0][tr + 64] = a1.x; As[tk4 + 1][tr + 64] = a1.y;
    As[tk4 + 2][tr + 64] = a1.z; As[tk4 + 3][tr + 64] = a1.w;
    *(float4*)&Bs[tkr][tc4]     = b0;
    *(float4*)&Bs[tkr + 8][tc4] = b1;
    __syncthreads();
#pragma unroll
    for (int k = 0; k < 16; ++k) {
      float a[8], b[8];
      *(float4*)(a)     = *(const float4*)&As[k][ty * 4];
      *(float4*)(a + 4) = *(const float4*)&As[k][ty * 4 + 64];
      *(float4*)(b)     = *(const float4*)&Bs[k][tx * 4];
      *(float4*)(b + 4) = *(const float4*)&Bs[k][tx * 4 + 64];
#pragma unroll
      for (int i = 0; i < 8; ++i)
#pragma unroll
        for (int j = 0; j < 8; ++j) acc[i][j] = fmaf(a[i], b[j], acc[i][j]);
    }
  }

#pragma unroll
  for (int i = 0; i < 8; ++i) {
    const int r = row0 + ty * 4 + (i & 3) + ((i >> 2) * 64);
    const float4 c0 = make_float4(acc[i][0], acc[i][1], acc[i][2], acc[i][3]);
    const float4 c1 = make_float4(acc[i][4], acc[i][5], acc[i][6], acc[i][7]);
    *(float4*)(C + (size_t)r * N + col0 + tx * 4)      = c0;
    *(float4*)(C + (size_t)r * N + col0 + tx * 4 + 64) = c1;
  }
}

// ---------------------------------------------------------------------------
// Attention with the reference's *direct* reshape:
//   head h, attention row s  <->  memory row l = h*128 + s/16,
//                                 columns (s%16)*64 .. +64 (+ part*1024)
// i.e. flat (L*D) plane per batch viewed as 32768 rows of 64; head h owns
// rows [h*2048, (h+1)*2048). Output scatter is the standard (B,L,H,KD).
// ---------------------------------------------------------------------------
__device__ __forceinline__ size_t head_row(int part, int b, int h, int s) {
  return ((size_t)(b * L_SEQ + h * 128 + (s >> 4))) * TD3 +
         (size_t)part * D_MODEL + (size_t)(s & 15) * HKD;
}

// One block = 64 query rows of one (b,h). 256 threads = 4 waves.
// Thread (ty,tx): S/O rows ty*4+i, cols tx+16*j. Flash/online softmax.
__global__ __launch_bounds__(256)
void attn_f32(const float* __restrict__ qkv, float* __restrict__ concat) {
  __shared__ float Qs[64][68];   // [row][k]   (68*4=272B rows: 16B aligned)
  __shared__ float Ks[64][68];   // [key][k]
  __shared__ float VsT[64][68];  // [d][key]   (transposed V)
  __shared__ float Ps[64][68];   // [row][key]

  const int t = threadIdx.x;
  const int tx = t & 15, ty = t >> 4;
  const int qt = blockIdx.x;
  const int b = blockIdx.y >> 4, h = blockIdx.y & 15;
  const int q0 = qt * 64;

  const int srow = t >> 4;        // staging row 0..15
  const int f4 = (t & 15) * 4;    // staging col group

  // stage Q tile once
#pragma unroll
  for (int rep = 0; rep < 4; ++rep) {
    const int s = srow + rep * 16;
    *(float4*)&Qs[s][f4] = *(const float4*)(qkv + head_row(0, b, h, q0 + s) + f4);
  }

  float m[4], l[4], o[4][4];
#pragma unroll
  for (int i = 0; i < 4; ++i) {
    m[i] = -1e30f; l[i] = 0.f;
#pragma unroll
    for (int j = 0; j < 4; ++j) o[i][j] = 0.f;
  }

  for (int kt = 0; kt <= qt; ++kt) {
    const int k0 = kt * 64;
    __syncthreads();  // previous iteration's LDS reads complete
#pragma unroll
    for (int rep = 0; rep < 4; ++rep) {
      const int s = srow + rep * 16;
      *(float4*)&Ks[s][f4] = *(const float4*)(qkv + head_row(1, b, h, k0 + s) + f4);
      const float4 vv = *(const float4*)(qkv + head_row(2, b, h, k0 + s) + f4);
      VsT[f4 + 0][s] = vv.x; VsT[f4 + 1][s] = vv.y;
      VsT[f4 + 2][s] = vv.z; VsT[f4 + 3][s] = vv.w;
    }
    __syncthreads();

    // S = Q K^T (raw)
    float sacc[4][4];
#pragma unroll
    for (int i = 0; i < 4; ++i)
#pragma unroll
      for (int j = 0; j < 4; ++j) sacc[i][j] = 0.f;
#pragma unroll
    for (int kk = 0; kk < 16; ++kk) {
      float4 qa[4], kb[4];
#pragma unroll
      for (int i = 0; i < 4; ++i) qa[i] = *(const float4*)&Qs[ty * 4 + i][kk * 4];
#pragma unroll
      for (int j = 0; j < 4; ++j) kb[j] = *(const float4*)&Ks[tx + 16 * j][kk * 4];
#pragma unroll
      for (int i = 0; i < 4; ++i)
#pragma unroll
        for (int j = 0; j < 4; ++j)
          sacc[i][j] = fmaf(qa[i].x, kb[j].x,
                       fmaf(qa[i].y, kb[j].y,
                       fmaf(qa[i].z, kb[j].z,
                       fmaf(qa[i].w, kb[j].w, sacc[i][j]))));
    }

    // scale, causal mask (diagonal tile only), online softmax
    const bool diag = (kt == qt);
#pragma unroll
    for (int i = 0; i < 4; ++i) {
      const int qrow = q0 + ty * 4 + i;
      float rm = -1e30f;
#pragma unroll
      for (int j = 0; j < 4; ++j) {
        float sv = sacc[i][j] * 0.125f;  // 1/sqrt(64)
        if (diag && (k0 + tx + 16 * j > qrow)) sv = -1e30f;
        sacc[i][j] = sv;
        rm = fmaxf(rm, sv);
      }
#pragma unroll
      for (int off = 8; off >= 1; off >>= 1)
        rm = fmaxf(rm, __shfl_xor(rm, off, 16));
      const float mnew = fmaxf(m[i], rm);
      const float sc = __expf(m[i] - mnew);
      float rs = 0.f;
#pragma unroll
      for (int j = 0; j < 4; ++j) {
        const float p = __expf(sacc[i][j] - mnew);
        rs += p;
        Ps[ty * 4 + i][tx + 16 * j] = p;
      }
#pragma unroll
      for (int off = 8; off >= 1; off >>= 1)
        rs += __shfl_xor(rs, off, 16);
      l[i] = l[i] * sc + rs;
      m[i] = mnew;
#pragma unroll
      for (int j = 0; j < 4; ++j) o[i][j] *= sc;
    }
    __syncthreads();  // Ps visible (also keeps waves in step before O phase)

    // O += P @ V  (VsT is [d][key])
#pragma unroll
    for (int kk = 0; kk < 16; ++kk) {
      float4 pa[4], vb[4];
#pragma unroll
      for (int i = 0; i < 4; ++i) pa[i] = *(const float4*)&Ps[ty * 4 + i][kk * 4];
#pragma unroll
      for (int j = 0; j < 4; ++j) vb[j] = *(const float4*)&VsT[tx + 16 * j][kk * 4];
#pragma unroll
      for (int i = 0; i < 4; ++i)
#pragma unroll
        for (int j = 0; j < 4; ++j)
          o[i][j] = fmaf(pa[i].x, vb[j].x,
                    fmaf(pa[i].y, vb[j].y,
                    fmaf(pa[i].z, vb[j].z,
                    fmaf(pa[i].w, vb[j].w, o[i][j]))));
    }
  }

  // epilogue: concat[b, q0+r, h*64 + d] = o / l
#pragma unroll
  for (int i = 0; i < 4; ++i) {
    const float inv = 1.0f / l[i];
    const size_t rowb =
        ((size_t)(b * L_SEQ + q0 + ty * 4 + i)) * D_MODEL + h * HKD;
#pragma unroll
    for (int j = 0; j < 4; ++j)
      concat[rowb + tx + 16 * j] = o[i][j] * inv;
  }
}

// ---------------------------------------------------------------------------
extern "C" void kernel_launch(void* const* d_in, const int* in_sizes, int n_in,
                              void* d_out, int out_size, void* d_ws, size_t ws_size,
                              hipStream_t stream) {
  const float* x    = (const float*)d_in[0];  // (2, 2048, 1024)
  const float* wqkv = (const float*)d_in[1];  // (1024, 3072)
  const float* wend = (const float*)d_in[2];  // (1024, 1024)
  float* out = (float*)d_out;                 // (2, 2048, 1024)

  float* qkv    = (float*)d_ws;                     // 4096*3072 f32 = 48 MB
  float* concat = qkv + (size_t)4096 * 3072;        // 4096*1024 f32 = 16 MB

  // qkv = x @ wqkv
  gemm_f32<<<dim3(3072 / 128, 4096 / 128), 256, 0, stream>>>(
      x, wqkv, qkv, 4096, 3072, 1024);
  // flash attention (causal) with the reference's direct reshape
  attn_f32<<<dim3(L_SEQ / 64, NBATCH * NH), 256, 0, stream>>>(qkv, concat);
  // out = concat @ wend
  gemm_f32<<<dim3(1024 / 128, 4096 / 128), 256, 0, stream>>>(
      concat, wend, out, 4096, 1024, 1024);
}

// Round 2
// 245.781 us; speedup vs baseline: 4.5413x; 4.5413x over previous
//
#include <hip/hip_runtime.h>
#include <cstddef>
#include <cstdint>

// (B, L, D, H) = (2, 2048, 1024, 16), KD = 64.
#define L_SEQ   2048
#define D_MODEL 1024
#define NH      16
#define HKD     64
#define TD3     3072
#define NBATCH  2

typedef __attribute__((ext_vector_type(8))) short bf16x8;
typedef __attribute__((ext_vector_type(4))) float f32x4;

__device__ __forceinline__ unsigned short f2bf(float f) {
  unsigned int u = __float_as_uint(f);
  u += 0x7fffu + ((u >> 16) & 1u);   // round-to-nearest-even
  return (unsigned short)(u >> 16);
}

__device__ __forceinline__ void gll16(const void* g, void* l) {
  __builtin_amdgcn_global_load_lds(
      (const __attribute__((address_space(1))) unsigned int*)g,
      (__attribute__((address_space(3))) unsigned int*)l, 16, 0, 0);
}

// ---------------------------------------------------------------------------
// fp32 -> bf16, 8 elems/thread
// ---------------------------------------------------------------------------
__global__ __launch_bounds__(256)
void cvt_f32_bf16(const float* __restrict__ in, unsigned short* __restrict__ out) {
  const int i = blockIdx.x * 256 + threadIdx.x;
  const float4 a = ((const float4*)in)[2 * i];
  const float4 b = ((const float4*)in)[2 * i + 1];
  bf16x8 v;
  v[0] = (short)f2bf(a.x); v[1] = (short)f2bf(a.y);
  v[2] = (short)f2bf(a.z); v[3] = (short)f2bf(a.w);
  v[4] = (short)f2bf(b.x); v[5] = (short)f2bf(b.y);
  v[6] = (short)f2bf(b.z); v[7] = (short)f2bf(b.w);
  ((bf16x8*)out)[i] = v;
}

// ---------------------------------------------------------------------------
// W[K][N] fp32 -> WT[N][K] bf16 (64x64 tiles through LDS)
// ---------------------------------------------------------------------------
__global__ __launch_bounds__(256)
void transpose_cvt(const float* __restrict__ W, unsigned short* __restrict__ WT,
                   int K, int N) {
  __shared__ unsigned short T[64][68];
  const int t = threadIdx.x;
  const int n0 = blockIdx.x * 64, k0 = blockIdx.y * 64;
  const int cr = t >> 4, cc = (t & 15) * 4;
#pragma unroll
  for (int i = 0; i < 4; ++i) {
    const int k = cr + 16 * i;
    const float4 v = *(const float4*)(W + (size_t)(k0 + k) * N + n0 + cc);
    T[cc + 0][k] = f2bf(v.x); T[cc + 1][k] = f2bf(v.y);
    T[cc + 2][k] = f2bf(v.z); T[cc + 3][k] = f2bf(v.w);
  }
  __syncthreads();
#pragma unroll
  for (int i = 0; i < 4; ++i) {
    const int n = cr + 16 * i;
    ushort4 o;
    o.x = T[n][cc]; o.y = T[n][cc + 1]; o.z = T[n][cc + 2]; o.w = T[n][cc + 3];
    *(ushort4*)(WT + (size_t)(n0 + n) * K + k0 + cc) = o;
  }
}

// ---------------------------------------------------------------------------
// bf16 MFMA GEMM, m97-style: C[M,N] = A[M,K] * Bt[N,K]^T.
// 128x128 tile, BK=64, 256 threads (4 waves, 2x2), 4x4 16x16x32 frags/wave.
// global_load_lds width-16 staging, linear LDS, 2-phase barrier structure.
// ---------------------------------------------------------------------------
template <typename OUT>
__device__ __forceinline__ OUT cvt_out(float f);
template <> __device__ __forceinline__ float cvt_out<float>(float f) { return f; }
template <> __device__ __forceinline__ unsigned short cvt_out<unsigned short>(float f) { return f2bf(f); }

template <typename OUT>
__global__ __launch_bounds__(256)
void gemm_bf16(const unsigned short* __restrict__ A,   // [M][K] bf16
               const unsigned short* __restrict__ Bt,  // [N][K] bf16
               OUT* __restrict__ C, int M, int N, int K) {
  __shared__ unsigned short As[128 * 64];
  __shared__ unsigned short Bs[128 * 64];
  const int t = threadIdx.x, w = t >> 6, lane = t & 63;
  const int lg = lane >> 4, lq = lane & 15;
  const int m0 = blockIdx.y * 128, n0 = blockIdx.x * 128;
  const int wr = w >> 1, wc = w & 1;

  f32x4 acc[4][4];
#pragma unroll
  for (int a = 0; a < 4; ++a)
#pragma unroll
    for (int b = 0; b < 4; ++b) acc[a][b] = (f32x4)0.f;

  for (int k0 = 0; k0 < K; k0 += 64) {
    __syncthreads();  // previous iteration's LDS reads done
#pragma unroll
    for (int i = 0; i < 4; ++i) {
      const int c = 256 * i + t;            // chunk 0..1023 (16B each)
      const int row = c >> 3, cc = (c & 7) * 8;
      gll16(A + (size_t)(m0 + row) * K + k0 + cc,
            (char*)As + (256 * i + 64 * w) * 16);
      gll16(Bt + (size_t)(n0 + row) * K + k0 + cc,
            (char*)Bs + (256 * i + 64 * w) * 16);
    }
    __syncthreads();  // drains vmcnt -> tiles ready
#pragma unroll
    for (int ks = 0; ks < 2; ++ks) {
      bf16x8 af[4], bfr[4];
#pragma unroll
      for (int mf = 0; mf < 4; ++mf)
        af[mf] = *(const bf16x8*)((const char*)As +
                   (wr * 64 + mf * 16 + lq) * 128 + ks * 64 + lg * 16);
#pragma unroll
      for (int nf = 0; nf < 4; ++nf)
        bfr[nf] = *(const bf16x8*)((const char*)Bs +
                   (wc * 64 + nf * 16 + lq) * 128 + ks * 64 + lg * 16);
#pragma unroll
      for (int mf = 0; mf < 4; ++mf)
#pragma unroll
        for (int nf = 0; nf < 4; ++nf)
          acc[mf][nf] = __builtin_amdgcn_mfma_f32_16x16x32_bf16(
              af[mf], bfr[nf], acc[mf][nf], 0, 0, 0);
    }
  }

  // C/D layout: col = lane&15, row = (lane>>4)*4 + reg  [m89]
#pragma unroll
  for (int mf = 0; mf < 4; ++mf)
#pragma unroll
    for (int nf = 0; nf < 4; ++nf) {
      const int col = n0 + wc * 64 + nf * 16 + lq;
#pragma unroll
      for (int r = 0; r < 4; ++r) {
        const int row = m0 + wr * 64 + mf * 16 + lg * 4 + r;
        C[(size_t)row * N + col] = cvt_out<OUT>(acc[mf][nf][r]);
      }
    }
}

// ---------------------------------------------------------------------------
// MFMA flash attention with the reference's direct reshape.
//   head h, attn row s  <->  memory row h*128 + s/16, cols (s%16)*64 (+part*D)
// Swapped operands: S^T = mfma(K, Q^T) -> lane owns q-column lq, keys in-lane.
// PV also swapped:  O^T = mfma(V^T, P^T) -> same lane layout, cheap rescale.
// ---------------------------------------------------------------------------
__device__ __forceinline__ size_t head_row(int part, int b, int h, int s) {
  return ((size_t)(b * L_SEQ + h * 128 + (s >> 4))) * TD3 +
         (size_t)part * D_MODEL + (size_t)(s & 15) * HKD;
}

__global__ __launch_bounds__(256)
void attn_mfma(const unsigned short* __restrict__ qkv,
               unsigned short* __restrict__ concat) {
  __shared__ unsigned short Ks[64 * 64];   // [key][d], chunk-XOR swizzled
  __shared__ unsigned short VT[64][72];    // [d][key], padded
  __shared__ unsigned short Pl[4][16][72]; // per-wave P[q][key], padded
  const int t = threadIdx.x, w = t >> 6, lane = t & 63;
  const int lg = lane >> 4, lq = lane & 15;
  const int qt = blockIdx.x, b = blockIdx.y >> 4, h = blockIdx.y & 15;
  const int q0 = qt * 64;
  const int qrow = q0 + w * 16 + lq;  // this lane's q (16-row strip per wave)

  // Q kept in registers as B-fragments (2 k-steps over the 64-dim)
  bf16x8 qf[2];
#pragma unroll
  for (int s = 0; s < 2; ++s)
    qf[s] = *(const bf16x8*)(qkv + head_row(0, b, h, qrow) + s * 32 + lg * 8);

  f32x4 o[4];
#pragma unroll
  for (int mf = 0; mf < 4; ++mf) o[mf] = (f32x4)0.f;
  float mrun = -1e30f, lrun = 0.f;

  const int vkey = t & 63;
  for (int kt = 0; kt <= qt; ++kt) {
    const int k0 = kt * 64;
    __syncthreads();  // previous tile's LDS reads done
    // K: global_load_lds, linear dest + inverse-swizzled source (m173)
#pragma unroll
    for (int i = 0; i < 2; ++i) {
      const int c = 256 * i + t;        // 0..511
      const int key = c >> 3, dc = c & 7;
      const int sdc = dc ^ (key & 7);
      gll16(qkv + head_row(1, b, h, k0 + key) + sdc * 8,
            (char*)Ks + (256 * i + 64 * w) * 16);
    }
    // V: reg-staged transpose (key-fastest lane mapping -> conflict-free writes)
#pragma unroll
    for (int i = 0; i < 2; ++i) {
      const int dc = (t >> 6) + 4 * i;
      const bf16x8 v = *(const bf16x8*)(qkv + head_row(2, b, h, k0 + vkey) + dc * 8);
#pragma unroll
      for (int j = 0; j < 8; ++j) VT[dc * 8 + j][vkey] = (unsigned short)v[j];
    }
    __syncthreads();  // vmcnt + lgkm drained

    // S^T = K * Q^T : lane holds S^T[key=16mf+4lg+r][q=lq]
    f32x4 s[4];
#pragma unroll
    for (int mf = 0; mf < 4; ++mf) s[mf] = (f32x4)0.f;
#pragma unroll
    for (int ks = 0; ks < 2; ++ks) {
      bf16x8 kf[4];
#pragma unroll
      for (int mf = 0; mf < 4; ++mf) {
        const int key = mf * 16 + lq;
        const int chunk = (lg + 4 * ks) ^ (key & 7);
        kf[mf] = *(const bf16x8*)((const char*)Ks + key * 128 + chunk * 16);
      }
#pragma unroll
      for (int mf = 0; mf < 4; ++mf)
        s[mf] = __builtin_amdgcn_mfma_f32_16x16x32_bf16(kf[mf], qf[ks], s[mf], 0, 0, 0);
    }

    // online softmax: 16 in-lane values + butterfly over the 4 lane-groups
    const bool diag = (kt == qt);
    float sv[16];
    float tmax = -1e30f;
#pragma unroll
    for (int mf = 0; mf < 4; ++mf)
#pragma unroll
      for (int r = 0; r < 4; ++r) {
        float x = s[mf][r] * 0.125f;  // 1/sqrt(64)
        if (diag && (k0 + mf * 16 + lg * 4 + r > qrow)) x = -1e30f;
        sv[mf * 4 + r] = x;
        tmax = fmaxf(tmax, x);
      }
    tmax = fmaxf(tmax, __shfl_xor(tmax, 16));
    tmax = fmaxf(tmax, __shfl_xor(tmax, 32));
    const float mnew = fmaxf(mrun, tmax);
    const float sc = __expf(mrun - mnew);
    float rs = 0.f;
#pragma unroll
    for (int mf = 0; mf < 4; ++mf) {
      const float p0 = __expf(sv[mf * 4 + 0] - mnew);
      const float p1 = __expf(sv[mf * 4 + 1] - mnew);
      const float p2 = __expf(sv[mf * 4 + 2] - mnew);
      const float p3 = __expf(sv[mf * 4 + 3] - mnew);
      rs += (p0 + p1) + (p2 + p3);
      ushort4 pk;
      pk.x = f2bf(p0); pk.y = f2bf(p1); pk.z = f2bf(p2); pk.w = f2bf(p3);
      *(ushort4*)&Pl[w][lq][mf * 16 + lg * 4] = pk;
    }
    rs += __shfl_xor(rs, 16);
    rs += __shfl_xor(rs, 32);
    lrun = lrun * sc + rs;
    mrun = mnew;
#pragma unroll
    for (int mf = 0; mf < 4; ++mf) {
      o[mf][0] *= sc; o[mf][1] *= sc; o[mf][2] *= sc; o[mf][3] *= sc;
    }

    // O^T += V^T * P^T  (lane owns q-column lq -> rescale was lane-local)
#pragma unroll
    for (int ks = 0; ks < 2; ++ks) {
      const bf16x8 pf = *(const bf16x8*)&Pl[w][lq][ks * 32 + lg * 8];
      bf16x8 vf[4];
#pragma unroll
      for (int mf = 0; mf < 4; ++mf)
        vf[mf] = *(const bf16x8*)&VT[mf * 16 + lq][ks * 32 + lg * 8];
#pragma unroll
      for (int mf = 0; mf < 4; ++mf)
        o[mf] = __builtin_amdgcn_mfma_f32_16x16x32_bf16(vf[mf], pf, o[mf], 0, 0, 0);
    }
  }

  // epilogue: concat[b][qrow][h*64 + d], d = 16mf + 4lg + r (pack 4)
  const float inv = 1.f / lrun;
#pragma unroll
  for (int mf = 0; mf < 4; ++mf) {
    ushort4 ov;
    ov.x = f2bf(o[mf][0] * inv); ov.y = f2bf(o[mf][1] * inv);
    ov.z = f2bf(o[mf][2] * inv); ov.w = f2bf(o[mf][3] * inv);
    *(ushort4*)(concat + (size_t)(b * L_SEQ + qrow) * D_MODEL + h * HKD +
                mf * 16 + lg * 4) = ov;
  }
}

// ---------------------------------------------------------------------------
extern "C" void kernel_launch(void* const* d_in, const int* in_sizes, int n_in,
                              void* d_out, int out_size, void* d_ws, size_t ws_size,
                              hipStream_t stream) {
  const float* x    = (const float*)d_in[0];  // (2, 2048, 1024)
  const float* wqkv = (const float*)d_in[1];  // (1024, 3072)
  const float* wend = (const float*)d_in[2];  // (1024, 1024)
  float* out = (float*)d_out;                 // (2, 2048, 1024) fp32

  char* ws = (char*)d_ws;
  unsigned short* qkv   = (unsigned short*)(ws);              // 24 MB bf16
  unsigned short* xb    = (unsigned short*)(ws + 25165824);   //  8 MB
  unsigned short* wqkvT = (unsigned short*)(ws + 33554432);   //  6 MB [3072][1024]
  unsigned short* wendT = (unsigned short*)(ws + 39845888);   //  2 MB [1024][1024]
  unsigned short* cat   = (unsigned short*)(ws + 41943040);   //  8 MB

  cvt_f32_bf16<<<2048, 256, 0, stream>>>(x, xb);
  transpose_cvt<<<dim3(48, 16), 256, 0, stream>>>(wqkv, wqkvT, 1024, 3072);
  transpose_cvt<<<dim3(16, 16), 256, 0, stream>>>(wend, wendT, 1024, 1024);

  // qkv = x @ wqkv   (M=4096, N=3072, K=1024) -> bf16
  gemm_bf16<unsigned short><<<dim3(24, 32), 256, 0, stream>>>(
      xb, wqkvT, qkv, 4096, 3072, 1024);
  // flash attention -> concat bf16
  attn_mfma<<<dim3(32, 32), 256, 0, stream>>>(qkv, cat);
  // out = concat @ wend  (M=4096, N=1024, K=1024) -> fp32
  gemm_bf16<float><<<dim3(8, 32), 256, 0, stream>>>(
      cat, wendT, out, 4096, 1024, 1024);
}

// Round 3
// 235.074 us; speedup vs baseline: 4.7481x; 1.0455x over previous
//
#include <hip/hip_runtime.h>
#include <cstddef>
#include <cstdint>

// (B, L, D, H) = (2, 2048, 1024, 16), KD = 64.
#define L_SEQ   2048
#define D_MODEL 1024
#define NH      16
#define HKD     64
#define TD3     3072
#define NBATCH  2

typedef __attribute__((ext_vector_type(8))) short bf16x8;
typedef __attribute__((ext_vector_type(4))) float f32x4;

__device__ __forceinline__ unsigned short f2bf(float f) {
  unsigned int u = __float_as_uint(f);
  u += 0x7fffu + ((u >> 16) & 1u);   // round-to-nearest-even
  return (unsigned short)(u >> 16);
}

__device__ __forceinline__ void gll16(const void* g, void* l) {
  __builtin_amdgcn_global_load_lds(
      (const __attribute__((address_space(1))) unsigned int*)g,
      (__attribute__((address_space(3))) unsigned int*)l, 16, 0, 0);
}

// ---------------------------------------------------------------------------
// fp32 -> bf16, 8 elems/thread
// ---------------------------------------------------------------------------
__global__ __launch_bounds__(256)
void cvt_f32_bf16(const float* __restrict__ in, unsigned short* __restrict__ out) {
  const int i = blockIdx.x * 256 + threadIdx.x;
  const float4 a = ((const float4*)in)[2 * i];
  const float4 b = ((const float4*)in)[2 * i + 1];
  bf16x8 v;
  v[0] = (short)f2bf(a.x); v[1] = (short)f2bf(a.y);
  v[2] = (short)f2bf(a.z); v[3] = (short)f2bf(a.w);
  v[4] = (short)f2bf(b.x); v[5] = (short)f2bf(b.y);
  v[6] = (short)f2bf(b.z); v[7] = (short)f2bf(b.w);
  ((bf16x8*)out)[i] = v;
}

// ---------------------------------------------------------------------------
// W[K][N] fp32 -> WT[N][K] bf16 (64x64 tiles through LDS)
// ---------------------------------------------------------------------------
__global__ __launch_bounds__(256)
void transpose_cvt(const float* __restrict__ W, unsigned short* __restrict__ WT,
                   int K, int N) {
  __shared__ unsigned short T[64][68];
  const int t = threadIdx.x;
  const int n0 = blockIdx.x * 64, k0 = blockIdx.y * 64;
  const int cr = t >> 4, cc = (t & 15) * 4;
#pragma unroll
  for (int i = 0; i < 4; ++i) {
    const int k = cr + 16 * i;
    const float4 v = *(const float4*)(W + (size_t)(k0 + k) * N + n0 + cc);
    T[cc + 0][k] = f2bf(v.x); T[cc + 1][k] = f2bf(v.y);
    T[cc + 2][k] = f2bf(v.z); T[cc + 3][k] = f2bf(v.w);
  }
  __syncthreads();
#pragma unroll
  for (int i = 0; i < 4; ++i) {
    const int n = cr + 16 * i;
    ushort4 o;
    o.x = T[n][cc]; o.y = T[n][cc + 1]; o.z = T[n][cc + 2]; o.w = T[n][cc + 3];
    *(ushort4*)(WT + (size_t)(n0 + n) * K + k0 + cc) = o;
  }
}

// ---------------------------------------------------------------------------
// bf16 MFMA GEMM, m97-style: C[M,N] = A[M,K] * Bt[N,K]^T.
// 128x128 tile, BK=64, 256 threads (4 waves, 2x2), 4x4 16x16x32 frags/wave.
// ---------------------------------------------------------------------------
template <typename OUT>
__device__ __forceinline__ OUT cvt_out(float f);
template <> __device__ __forceinline__ float cvt_out<float>(float f) { return f; }
template <> __device__ __forceinline__ unsigned short cvt_out<unsigned short>(float f) { return f2bf(f); }

template <typename OUT>
__global__ __launch_bounds__(256)
void gemm_bf16(const unsigned short* __restrict__ A,   // [M][K] bf16
               const unsigned short* __restrict__ Bt,  // [N][K] bf16
               OUT* __restrict__ C, int M, int N, int K) {
  __shared__ unsigned short As[128 * 64];
  __shared__ unsigned short Bs[128 * 64];
  const int t = threadIdx.x, w = t >> 6, lane = t & 63;
  const int lg = lane >> 4, lq = lane & 15;
  const int m0 = blockIdx.y * 128, n0 = blockIdx.x * 128;
  const int wr = w >> 1, wc = w & 1;

  f32x4 acc[4][4];
#pragma unroll
  for (int a = 0; a < 4; ++a)
#pragma unroll
    for (int b = 0; b < 4; ++b) acc[a][b] = (f32x4)0.f;

  for (int k0 = 0; k0 < K; k0 += 64) {
    __syncthreads();  // previous iteration's LDS reads done
#pragma unroll
    for (int i = 0; i < 4; ++i) {
      const int c = 256 * i + t;            // chunk 0..1023 (16B each)
      const int row = c >> 3, cc = (c & 7) * 8;
      gll16(A + (size_t)(m0 + row) * K + k0 + cc,
            (char*)As + (256 * i + 64 * w) * 16);
      gll16(Bt + (size_t)(n0 + row) * K + k0 + cc,
            (char*)Bs + (256 * i + 64 * w) * 16);
    }
    __syncthreads();  // drains vmcnt -> tiles ready
#pragma unroll
    for (int ks = 0; ks < 2; ++ks) {
      bf16x8 af[4], bfr[4];
#pragma unroll
      for (int mf = 0; mf < 4; ++mf)
        af[mf] = *(const bf16x8*)((const char*)As +
                   (wr * 64 + mf * 16 + lq) * 128 + ks * 64 + lg * 16);
#pragma unroll
      for (int nf = 0; nf < 4; ++nf)
        bfr[nf] = *(const bf16x8*)((const char*)Bs +
                   (wc * 64 + nf * 16 + lq) * 128 + ks * 64 + lg * 16);
#pragma unroll
      for (int mf = 0; mf < 4; ++mf)
#pragma unroll
        for (int nf = 0; nf < 4; ++nf)
          acc[mf][nf] = __builtin_amdgcn_mfma_f32_16x16x32_bf16(
              af[mf], bfr[nf], acc[mf][nf], 0, 0, 0);
    }
  }

  // C/D layout: col = lane&15, row = (lane>>4)*4 + reg  [m89]
#pragma unroll
  for (int mf = 0; mf < 4; ++mf)
#pragma unroll
    for (int nf = 0; nf < 4; ++nf) {
      const int col = n0 + wc * 64 + nf * 16 + lq;
#pragma unroll
      for (int r = 0; r < 4; ++r) {
        const int row = m0 + wr * 64 + mf * 16 + lg * 4 + r;
        C[(size_t)row * N + col] = cvt_out<OUT>(acc[mf][nf][r]);
      }
    }
}

// ---------------------------------------------------------------------------
// Reference's direct reshape: head h, attn row s <-> memory row h*128 + s/16,
// cols (s%16)*64 (+ part*D_MODEL).
// ---------------------------------------------------------------------------
__device__ __forceinline__ size_t head_row(int part, int b, int h, int s) {
  return ((size_t)(b * L_SEQ + h * 128 + (s >> 4))) * TD3 +
         (size_t)part * D_MODEL + (size_t)(s & 15) * HKD;
}

// ---------------------------------------------------------------------------
// V pre-transpose: vT[b][h][d][s]  (so attention can gll16 V^T tiles linearly)
// ---------------------------------------------------------------------------
__global__ __launch_bounds__(256)
void transpose_v(const unsigned short* __restrict__ qkv,
                 unsigned short* __restrict__ vT) {
  __shared__ unsigned short T[64][68];
  const int t = threadIdx.x;
  const int kt = blockIdx.x, bh = blockIdx.y, b = bh >> 4, h = bh & 15;
  const int s0 = kt * 64;
  const int sr = t >> 4, c4 = (t & 15) * 4;
#pragma unroll
  for (int i = 0; i < 4; ++i) {
    const int s = sr + 16 * i;
    const ushort4 v = *(const ushort4*)(qkv + head_row(2, b, h, s0 + s) + c4);
    T[c4 + 0][s] = v.x; T[c4 + 1][s] = v.y;
    T[c4 + 2][s] = v.z; T[c4 + 3][s] = v.w;
  }
  __syncthreads();
#pragma unroll
  for (int i = 0; i < 4; ++i) {
    const int d = sr + 16 * i;
    ushort4 o;
    o.x = T[d][c4]; o.y = T[d][c4 + 1]; o.z = T[d][c4 + 2]; o.w = T[d][c4 + 3];
    *(ushort4*)(vT + ((size_t)(bh * 64 + d)) * L_SEQ + s0 + c4) = o;
  }
}

// ---------------------------------------------------------------------------
// MFMA flash attention, QBLK=128 (8 waves), KVBLK=64, double-buffered K/V^T
// staged by global_load_lds (one barrier per tile -> staging hides under
// compute). Swapped operands: S^T = mfma(K, Q^T), O^T = mfma(V^T, P^T).
// ---------------------------------------------------------------------------
__global__ __launch_bounds__(512)
void attn_mfma(const unsigned short* __restrict__ qkv,
               const unsigned short* __restrict__ vT,
               unsigned short* __restrict__ concat) {
  __shared__ unsigned short Ks[2][64 * 64];  // [key][d], chunk-XOR swizzled
  __shared__ unsigned short Vs[2][64 * 64];  // [d][key], chunk-XOR swizzled
  __shared__ unsigned short Pl[8][16][72];   // per-wave P[q][key], padded

  const int t = threadIdx.x, w = t >> 6, lane = t & 63;
  const int lg = lane >> 4, lq = lane & 15;
  const int qt = 15 - blockIdx.x;            // heavy blocks first
  const int bh = blockIdx.y, b = bh >> 4, h = bh & 15;
  const int q0 = qt * 128;
  const int qrow = q0 + w * 16 + lq;         // this lane's q row

  // Q fragments (64-dim in 2 k-steps), kept in registers
  bf16x8 qf[2];
  {
    const size_t qb = head_row(0, b, h, qrow) + lg * 8;
    qf[0] = *(const bf16x8*)(qkv + qb);
    qf[1] = *(const bf16x8*)(qkv + qb + 32);
  }

  // staging constants: thread t stages 16B chunk c=t of each 64x64 tile.
  // dest is linear; source column is XOR-swizzled (involution, read applies same).
  const int skey = t >> 3, sdc = t & 7;
  const int swz = (sdc ^ (skey & 7)) * 8;
  const size_t kSrc0 = head_row(1, b, h, skey) + swz;           // += k0*192
  const size_t vSrc0 = ((size_t)(bh * 64 + skey)) * L_SEQ + swz; // += k0
  char* const kDst = (char*)&Ks[0][0] + w * 1024;
  char* const vDst = (char*)&Vs[0][0] + w * 1024;

  f32x4 o[4];
#pragma unroll
  for (int mf = 0; mf < 4; ++mf) o[mf] = (f32x4)0.f;
  float mrun = -1e30f, lrun = 0.f;

  const int ktmax = 2 * qt + 1;

  // prologue: stage tile 0 into buffer 0
  gll16(qkv + kSrc0, kDst);
  gll16(vT + vSrc0, vDst);

  for (int kt = 0; kt <= ktmax; ++kt) {
    const int k0 = kt * 64;
    const int cur = kt & 1;
    __syncthreads();  // vmcnt drained: buf[cur] ready; buf[1-cur] reads done

    if (kt < ktmax) {  // issue next tile into the other buffer (overlaps compute)
      gll16(qkv + kSrc0 + (size_t)(k0 + 64) * 192, kDst + (1 - cur) * 8192);
      gll16(vT + vSrc0 + (size_t)(k0 + 64), vDst + (1 - cur) * 8192);
    }
    const char* kb = (const char*)&Ks[cur][0];
    const char* vb = (const char*)&Vs[cur][0];

    // S^T = K * Q^T : lane holds S^T[key=16mf+4lg+r][q=lq]
    f32x4 s[4];
#pragma unroll
    for (int mf = 0; mf < 4; ++mf) s[mf] = (f32x4)0.f;
    __builtin_amdgcn_s_setprio(1);
#pragma unroll
    for (int ks = 0; ks < 2; ++ks) {
      bf16x8 kf[4];
#pragma unroll
      for (int mf = 0; mf < 4; ++mf) {
        const int key = mf * 16 + lq;
        const int chunk = (lg + 4 * ks) ^ (key & 7);
        kf[mf] = *(const bf16x8*)(kb + key * 128 + chunk * 16);
      }
#pragma unroll
      for (int mf = 0; mf < 4; ++mf)
        s[mf] = __builtin_amdgcn_mfma_f32_16x16x32_bf16(kf[mf], qf[ks], s[mf], 0, 0, 0);
    }
    __builtin_amdgcn_s_setprio(0);

    // online softmax (16 in-lane values + butterfly over 4 lane-groups)
    float sv[16];
    float tmax = -1e30f;
#pragma unroll
    for (int mf = 0; mf < 4; ++mf)
#pragma unroll
      for (int r = 0; r < 4; ++r) {
        float x = s[mf][r] * 0.125f;  // 1/sqrt(64)
        if (k0 + mf * 16 + lg * 4 + r > qrow) x = -1e30f;  // causal
        sv[mf * 4 + r] = x;
        tmax = fmaxf(tmax, x);
      }
    tmax = fmaxf(tmax, __shfl_xor(tmax, 16));
    tmax = fmaxf(tmax, __shfl_xor(tmax, 32));
    const float mnew = fmaxf(mrun, tmax);
    const float sc = __expf(mrun - mnew);
    float rs = 0.f;
#pragma unroll
    for (int mf = 0; mf < 4; ++mf) {
      const float p0 = __expf(sv[mf * 4 + 0] - mnew);
      const float p1 = __expf(sv[mf * 4 + 1] - mnew);
      const float p2 = __expf(sv[mf * 4 + 2] - mnew);
      const float p3 = __expf(sv[mf * 4 + 3] - mnew);
      rs += (p0 + p1) + (p2 + p3);
      ushort4 pk;
      pk.x = f2bf(p0); pk.y = f2bf(p1); pk.z = f2bf(p2); pk.w = f2bf(p3);
      *(ushort4*)&Pl[w][lq][mf * 16 + lg * 4] = pk;
    }
    rs += __shfl_xor(rs, 16);
    rs += __shfl_xor(rs, 32);
    lrun = lrun * sc + rs;
    mrun = mnew;
#pragma unroll
    for (int mf = 0; mf < 4; ++mf) {
      o[mf][0] *= sc; o[mf][1] *= sc; o[mf][2] *= sc; o[mf][3] *= sc;
    }

    // O^T += V^T * P^T   (per-wave Pl strip: same-wave write->read, no barrier)
    __builtin_amdgcn_s_setprio(1);
#pragma unroll
    for (int ks = 0; ks < 2; ++ks) {
      const bf16x8 pf = *(const bf16x8*)&Pl[w][lq][ks * 32 + lg * 8];
      bf16x8 vf[4];
#pragma unroll
      for (int mf = 0; mf < 4; ++mf) {
        const int d = mf * 16 + lq;
        const int chunk = (lg + 4 * ks) ^ (d & 7);
        vf[mf] = *(const bf16x8*)(vb + d * 128 + chunk * 16);
      }
#pragma unroll
      for (int mf = 0; mf < 4; ++mf)
        o[mf] = __builtin_amdgcn_mfma_f32_16x16x32_bf16(vf[mf], pf, o[mf], 0, 0, 0);
    }
    __builtin_amdgcn_s_setprio(0);
  }

  // epilogue: concat[b][qrow][h*64 + d], d = 16mf + 4lg + r
  const float inv = 1.f / lrun;
#pragma unroll
  for (int mf = 0; mf < 4; ++mf) {
    ushort4 ov;
    ov.x = f2bf(o[mf][0] * inv); ov.y = f2bf(o[mf][1] * inv);
    ov.z = f2bf(o[mf][2] * inv); ov.w = f2bf(o[mf][3] * inv);
    *(ushort4*)(concat + (size_t)(b * L_SEQ + qrow) * D_MODEL + h * HKD +
                mf * 16 + lg * 4) = ov;
  }
}

// ---------------------------------------------------------------------------
extern "C" void kernel_launch(void* const* d_in, const int* in_sizes, int n_in,
                              void* d_out, int out_size, void* d_ws, size_t ws_size,
                              hipStream_t stream) {
  const float* x    = (const float*)d_in[0];  // (2, 2048, 1024)
  const float* wqkv = (const float*)d_in[1];  // (1024, 3072)
  const float* wend = (const float*)d_in[2];  // (1024, 1024)
  float* out = (float*)d_out;                 // (2, 2048, 1024) fp32

  char* ws = (char*)d_ws;
  unsigned short* qkv   = (unsigned short*)(ws);              // 24 MB bf16
  unsigned short* xb    = (unsigned short*)(ws + 25165824);   //  8 MB (x bf16; dead after GEMM1 -> reused as vT)
  unsigned short* wqkvT = (unsigned short*)(ws + 33554432);   //  6 MB [3072][1024]
  unsigned short* wendT = (unsigned short*)(ws + 39845888);   //  2 MB [1024][1024]
  unsigned short* cat   = (unsigned short*)(ws + 41943040);   //  8 MB
  unsigned short* vT    = xb;                                 //  8 MB [32][64][2048]

  cvt_f32_bf16<<<2048, 256, 0, stream>>>(x, xb);
  transpose_cvt<<<dim3(48, 16), 256, 0, stream>>>(wqkv, wqkvT, 1024, 3072);
  transpose_cvt<<<dim3(16, 16), 256, 0, stream>>>(wend, wendT, 1024, 1024);

  // qkv = x @ wqkv   (M=4096, N=3072, K=1024) -> bf16
  gemm_bf16<unsigned short><<<dim3(24, 32), 256, 0, stream>>>(
      xb, wqkvT, qkv, 4096, 3072, 1024);
  // V^T pre-transpose (xb is dead now; vT aliases it)
  transpose_v<<<dim3(32, 32), 256, 0, stream>>>(qkv, vT);
  // flash attention -> concat bf16
  attn_mfma<<<dim3(16, 32), 512, 0, stream>>>(qkv, vT, cat);
  // out = concat @ wend  (M=4096, N=1024, K=1024) -> fp32
  gemm_bf16<float><<<dim3(8, 32), 256, 0, stream>>>(
      cat, wendT, out, 4096, 1024, 1024);
}